// Round 1
// baseline (18738.072 us; speedup 1.0000x reference)
//
#include <hip/hip_runtime.h>

// LSTM: B=H=1024, S=128, I=1024.
// Per step t: gates = x[:,t,:] @ Wx(1024x4096) + h @ Wh(1024x4096) + bias
//             i,f,o = sigmoid; g = tanh; c = f*c + i*g; h = o*tanh(c)
// Strategy: one fused MFMA kernel per timestep (128 launches), bf16 inputs /
// fp32 accum. Block = 64(b) x 64(h) x 4 gates; 4 waves split by m-rows so the
// LSTM elementwise update is register-local (no barriers in the kernel).
// Weights pre-transposed to wT[mat][h][k] bf16 in ws for contiguous B-frags.

#define Hdim 1024
#define Sdim 128
#define Idim 1024

typedef __attribute__((ext_vector_type(8))) short short8;
typedef __attribute__((ext_vector_type(4))) float floatx4;

static __device__ __forceinline__ short f2bf(float f) {
  // round-to-nearest-even fp32 -> bf16 (finite inputs)
  unsigned u = __float_as_uint(f);
  u += 0x7fffu + ((u >> 16) & 1u);
  return (short)(u >> 16);
}

// ---- weight transpose + fp32->bf16 convert: dst[h][k] = src[k][h] ----
__global__ __launch_bounds__(256) void wtrans(const float* __restrict__ src,
                                              unsigned short* __restrict__ dst) {
  __shared__ float tile[32][33];
  int h0 = blockIdx.x * 32, k0 = blockIdx.y * 32;
  int tx = threadIdx.x & 31, ty = threadIdx.x >> 5;  // 32 x 8
#pragma unroll
  for (int r = ty; r < 32; r += 8)
    tile[r][tx] = src[((size_t)(k0 + r) << 10) + h0 + tx];
  __syncthreads();
#pragma unroll
  for (int r = ty; r < 32; r += 8)
    dst[((size_t)(h0 + r) << 10) + k0 + tx] = (unsigned short)f2bf(tile[tx][r]);
}

// ---- combined bias: bias_c[g][h] = b_i<g>[h] + b_h<g>[h] ----
__global__ void bias_combine(const float* __restrict__ b0, const float* __restrict__ b1,
                             const float* __restrict__ b2, const float* __restrict__ b3,
                             const float* __restrict__ b4, const float* __restrict__ b5,
                             const float* __restrict__ b6, const float* __restrict__ b7,
                             float* __restrict__ bias_c) {
  int i = blockIdx.x * 256 + threadIdx.x;  // 0..4095
  int g = i >> 10, h = i & 1023;
  const float* pa;
  const float* pb;
  switch (g) {
    case 0: pa = b0; pb = b1; break;
    case 1: pa = b2; pb = b3; break;
    case 2: pa = b4; pb = b5; break;
    default: pa = b6; pb = b7; break;
  }
  bias_c[i] = pa[h] + pb[h];
}

// ---- fused per-timestep kernel ----
// grid (16,16): blockIdx.x -> h tile (64 cols), blockIdx.y -> b tile (64 rows)
// 4 waves: wave w owns rows [w*16, w*16+16) x 64 cols x 4 gates.
__global__ __launch_bounds__(256) void lstm_step(
    const float* __restrict__ x,              // (1024, 128, 1024) fp32
    const unsigned short* __restrict__ hprev, // (1024, 1024) bf16
    unsigned short* __restrict__ hnext,       // (1024, 1024) bf16
    float* __restrict__ c_ws,                 // (1024, 1024) fp32
    const unsigned short* __restrict__ wT,    // [8][1024][1024] bf16, [mat][h][k]
    const float* __restrict__ bias_c,         // [4][1024] fp32
    float* __restrict__ out,                  // d_out: h (1M fp32) then c (1M fp32)
    int t, int last) {
  int wave = threadIdx.x >> 6;
  int lane = threadIdx.x & 63;
  int ln = lane & 15;   // n (B-frag col) / m (A-frag row) / output col
  int lq = lane >> 4;   // quad
  int b0 = blockIdx.y * 64;
  int h0 = blockIdx.x * 64;
  int arow = b0 + wave * 16 + ln;  // A-operand row for this lane

  floatx4 acc[4][4];  // [gate][ntile]
#pragma unroll
  for (int g = 0; g < 4; ++g)
#pragma unroll
    for (int n = 0; n < 4; ++n)
      acc[g][n] = (floatx4){0.f, 0.f, 0.f, 0.f};

  // ---- phase 1: x_t @ Wx (A = fp32 x, converted in-register) ----
  {
    const float* xp = x + ((size_t)arow * Sdim + t) * Idim + lq * 8;
#pragma unroll 1
    for (int k0 = 0; k0 < Idim; k0 += 32) {
      floatx4 f0 = *(const floatx4*)(xp + k0);
      floatx4 f1 = *(const floatx4*)(xp + k0 + 4);
      short8 a;
#pragma unroll
      for (int j = 0; j < 4; ++j) {
        a[j] = f2bf(f0[j]);
        a[4 + j] = f2bf(f1[j]);
      }
#pragma unroll
      for (int g = 0; g < 4; ++g) {
#pragma unroll
        for (int n = 0; n < 4; ++n) {
          const unsigned short* bp =
              wT + ((size_t)(g * 2) << 20) + ((size_t)(h0 + n * 16 + ln) << 10) + k0 + lq * 8;
          short8 b = *(const short8*)bp;
          acc[g][n] = __builtin_amdgcn_mfma_f32_16x16x32_bf16(a, b, acc[g][n], 0, 0, 0);
        }
      }
    }
  }

  // ---- phase 2: h_prev @ Wh (A = bf16 h) ----
  {
    const unsigned short* hp = hprev + ((size_t)arow << 10) + lq * 8;
#pragma unroll 1
    for (int k0 = 0; k0 < Hdim; k0 += 32) {
      short8 a = *(const short8*)(hp + k0);
#pragma unroll
      for (int g = 0; g < 4; ++g) {
#pragma unroll
        for (int n = 0; n < 4; ++n) {
          const unsigned short* bp =
              wT + ((size_t)(g * 2 + 1) << 20) + ((size_t)(h0 + n * 16 + ln) << 10) + k0 + lq * 8;
          short8 b = *(const short8*)bp;
          acc[g][n] = __builtin_amdgcn_mfma_f32_16x16x32_bf16(a, b, acc[g][n], 0, 0, 0);
        }
      }
    }
  }

  // ---- epilogue: register-local LSTM update ----
  // C/D layout (16x16x32): col = lane&15, row = (lane>>4)*4 + reg
  int brow = b0 + wave * 16 + lq * 4;
#pragma unroll
  for (int n = 0; n < 4; ++n) {
    int hcol = h0 + n * 16 + ln;
    float bi = bias_c[hcol];
    float bf_ = bias_c[1024 + hcol];
    float bg = bias_c[2048 + hcol];
    float bo = bias_c[3072 + hcol];
#pragma unroll
    for (int r = 0; r < 4; ++r) {
      size_t idx = ((size_t)(brow + r) << 10) + hcol;
      float pi = acc[0][n][r] + bi;
      float pf = acc[1][n][r] + bf_;
      float pg = acc[2][n][r] + bg;
      float po = acc[3][n][r] + bo;
      float gi = 1.f / (1.f + __expf(-pi));
      float gf = 1.f / (1.f + __expf(-pf));
      float gg = 2.f / (1.f + __expf(-2.f * pg)) - 1.f;  // tanh
      float go = 1.f / (1.f + __expf(-po));
      float cn = gf * c_ws[idx] + gi * gg;
      float hn = go * (2.f / (1.f + __expf(-2.f * cn)) - 1.f);
      c_ws[idx] = cn;
      hnext[idx] = (unsigned short)f2bf(hn);
      if (last) {
        out[idx] = hn;                 // h_t
        out[(1u << 20) + idx] = cn;    // c_t
      }
    }
  }
}

extern "C" void kernel_launch(void* const* d_in, const int* in_sizes, int n_in,
                              void* d_out, int out_size, void* d_ws, size_t ws_size,
                              hipStream_t stream) {
  const float* x = (const float*)d_in[0];
  char* ws = (char*)d_ws;
  // ws layout: wT 16MB | h0 2MB | h1 2MB | c 4MB | bias 16KB  (~24 MB total)
  unsigned short* wT = (unsigned short*)ws;
  unsigned short* hbuf0 = (unsigned short*)(ws + (16u << 20));
  unsigned short* hbuf1 = (unsigned short*)(ws + (18u << 20));
  float* c_ws = (float*)(ws + (20u << 20));
  float* bias_c = (float*)(ws + (24u << 20));

  // d_in order: x, w_ii, w_hi, w_if, w_hf, w_ig, w_hg, w_io, w_ho, b_ii..b_ho
  for (int j = 0; j < 8; ++j) {
    wtrans<<<dim3(32, 32), 256, 0, stream>>>((const float*)d_in[1 + j],
                                             wT + ((size_t)j << 20));
  }
  bias_combine<<<16, 256, 0, stream>>>(
      (const float*)d_in[9], (const float*)d_in[10], (const float*)d_in[11],
      (const float*)d_in[12], (const float*)d_in[13], (const float*)d_in[14],
      (const float*)d_in[15], (const float*)d_in[16], bias_c);

  hipMemsetAsync(hbuf0, 0, 2u << 20, stream);  // h0 = 0 (bf16 zeros)
  hipMemsetAsync(c_ws, 0, 4u << 20, stream);   // c0 = 0

  float* out = (float*)d_out;
  for (int t = 0; t < Sdim; ++t) {
    const unsigned short* hp = (t & 1) ? hbuf1 : hbuf0;
    unsigned short* hn = (t & 1) ? hbuf0 : hbuf1;
    lstm_step<<<dim3(16, 16), 256, 0, stream>>>(x, hp, hn, c_ws, wT, bias_c, out,
                                                t, t == Sdim - 1);
  }
}

// Round 2
// 6730.168 us; speedup vs baseline: 2.7842x; 2.7842x over previous
//
#include <hip/hip_runtime.h>

// LSTM: B=H=1024, S=128, I=1024.
// Round 2: (1) hoist x@Wx into a big parallel MFMA GEMM (chunked by ws_size),
// (2) step kernel = LDS-staged h@Wh with global_load_lds + fused LSTM epilogue.
// ws layout: wT 16MB | bias 16KB @16M | h0 @17M | h1 @19M | c @21M (4MB)
//            | xb (Tc*2MB) @25M | xp (Tc*8MB) after.

#define Hdim 1024
#define Sdim 128

typedef __attribute__((ext_vector_type(8))) short short8;
typedef __attribute__((ext_vector_type(4))) float floatx4;

#define GLDS(gp, lp)                                                     \
  __builtin_amdgcn_global_load_lds(                                      \
      (const __attribute__((address_space(1))) void*)(gp),               \
      (__attribute__((address_space(3))) void*)(lp), 16, 0, 0)

static __device__ __forceinline__ short f2bf(float f) {
  unsigned u = __float_as_uint(f);
  u += 0x7fffu + ((u >> 16) & 1u);
  return (short)(u >> 16);
}
static __device__ __forceinline__ float bf2f(unsigned short u) {
  return __uint_as_float((unsigned)u << 16);
}

// ---- weight transpose + convert: dst[h][k] = src[k][h] (bf16) ----
__global__ __launch_bounds__(256) void wtrans(const float* __restrict__ src,
                                              unsigned short* __restrict__ dst) {
  __shared__ float tile[32][33];
  int h0 = blockIdx.x * 32, k0 = blockIdx.y * 32;
  int tx = threadIdx.x & 31, ty = threadIdx.x >> 5;
#pragma unroll
  for (int r = ty; r < 32; r += 8)
    tile[r][tx] = src[((size_t)(k0 + r) << 10) + h0 + tx];
  __syncthreads();
#pragma unroll
  for (int r = ty; r < 32; r += 8)
    dst[((size_t)(h0 + r) << 10) + k0 + tx] = (unsigned short)f2bf(tile[tx][r]);
}

// ---- combined bias ----
__global__ void bias_combine(const float* __restrict__ b0, const float* __restrict__ b1,
                             const float* __restrict__ b2, const float* __restrict__ b3,
                             const float* __restrict__ b4, const float* __restrict__ b5,
                             const float* __restrict__ b6, const float* __restrict__ b7,
                             float* __restrict__ bias_c) {
  int i = blockIdx.x * 256 + threadIdx.x;
  int g = i >> 10, h = i & 1023;
  const float *pa, *pb;
  switch (g) {
    case 0: pa = b0; pb = b1; break;
    case 1: pa = b2; pb = b3; break;
    case 2: pa = b4; pb = b5; break;
    default: pa = b6; pb = b7; break;
  }
  bias_c[i] = pa[h] + pb[h];
}

// ---- x fp32 -> xb bf16, chunk layout xb[b][tc][k] ----
__global__ __launch_bounds__(256) void xconv(const float* __restrict__ x,
                                             unsigned short* __restrict__ xb,
                                             int t0, int Tcur) {
  int tc = blockIdx.y;
  int tid8 = (blockIdx.x * 256 + threadIdx.x) * 8;
  int b = tid8 >> 10, k = tid8 & 1023;
  const float* src = x + ((((size_t)b << 7) + t0 + tc) << 10) + k;
  floatx4 f0 = *(const floatx4*)src;
  floatx4 f1 = *(const floatx4*)(src + 4);
  short8 o;
#pragma unroll
  for (int j = 0; j < 4; ++j) {
    o[j] = f2bf(f0[j]);
    o[4 + j] = f2bf(f1[j]);
  }
  *(short8*)(xb + (((size_t)b * Tcur + tc) << 10) + k) = o;
}

// ---- big GEMM: xp[tc][b][g*1024+h] = xb[b][tc][:] @ Wx_g[:, h] (bf16 out) ----
// grid: (32 ntiles, Tcur*8 mtiles), 256 threads, 128x128 tile, BK=32.
__global__ __launch_bounds__(256) void xgemm(const unsigned short* __restrict__ xb,
                                             const unsigned short* __restrict__ wT,
                                             unsigned short* __restrict__ xp,
                                             int Tcur) {
  __shared__ unsigned short As[128 * 32];
  __shared__ unsigned short Bs[128 * 32];
  int tid = threadIdx.x;
  int wave = tid >> 6, lane = tid & 63;
  int ln = lane & 15, lq = lane >> 4;
  int wm = wave & 1, wn = wave >> 1;
  int srow = lane >> 2, scol = (lane & 3) * 8;  // staging: 16 rows x 64B per instr
  int nt = blockIdx.x;
  int g = nt >> 3;
  int h0 = (nt & 7) * 128;
  int mt = blockIdx.y;
  int tc = mt >> 3;
  int b0 = (mt & 7) * 128;
  const unsigned short* wx = wT + ((size_t)(2 * g) << 20);

  floatx4 acc[4][4];
#pragma unroll
  for (int i = 0; i < 4; ++i)
#pragma unroll
    for (int j = 0; j < 4; ++j) acc[i][j] = (floatx4){0.f, 0.f, 0.f, 0.f};

#pragma unroll 1
  for (int k0 = 0; k0 < 1024; k0 += 32) {
    __syncthreads();
#pragma unroll
    for (int i = 0; i < 2; ++i) {
      int q = wave * 2 + i;
      GLDS(xb + (((size_t)(b0 + q * 16 + srow) * Tcur + tc) << 10) + k0 + scol,
           (char*)As + q * 1024 + lane * 16);
      GLDS(wx + ((size_t)(h0 + q * 16 + srow) << 10) + k0 + scol,
           (char*)Bs + q * 1024 + lane * 16);
    }
    __syncthreads();
    short8 a[4], b[4];
#pragma unroll
    for (int i = 0; i < 4; ++i)
      a[i] = *(const short8*)(As + (wm * 64 + i * 16 + ln) * 32 + lq * 8);
#pragma unroll
    for (int j = 0; j < 4; ++j)
      b[j] = *(const short8*)(Bs + (wn * 64 + j * 16 + ln) * 32 + lq * 8);
#pragma unroll
    for (int i = 0; i < 4; ++i)
#pragma unroll
      for (int j = 0; j < 4; ++j)
        acc[i][j] = __builtin_amdgcn_mfma_f32_16x16x32_bf16(a[i], b[j], acc[i][j], 0, 0, 0);
  }

  size_t rowbase = (size_t)tc << 10;
#pragma unroll
  for (int i = 0; i < 4; ++i) {
    int brow = b0 + wm * 64 + i * 16 + lq * 4;
#pragma unroll
    for (int j = 0; j < 4; ++j) {
      int col = g * 1024 + h0 + wn * 64 + j * 16 + ln;
#pragma unroll
      for (int r = 0; r < 4; ++r)
        xp[((rowbase + brow + r) << 12) + col] = (unsigned short)f2bf(acc[i][j][r]);
    }
  }
}

// ---- per-step: gates = h@Wh + xp[tc] + bias -> LSTM update ----
// grid (32 htiles, 8 btiles), 256 threads. Block: 128b x 32h x 4 gates, BK=32.
__global__ __launch_bounds__(256) void lstm_step(
    const unsigned short* __restrict__ hprev, unsigned short* __restrict__ hnext,
    float* __restrict__ c_ws, const unsigned short* __restrict__ wT,
    const float* __restrict__ bias_c, const unsigned short* __restrict__ xp,
    float* __restrict__ out, int tc, int last) {
  __shared__ unsigned short As[128 * 32];      // h rows [128b][32k]
  __shared__ unsigned short Bs[4 * 32 * 32];   // [g][32h][32k]
  int tid = threadIdx.x;
  int wave = tid >> 6, lane = tid & 63;
  int ln = lane & 15, lq = lane >> 4;
  int srow = lane >> 2, scol = (lane & 3) * 8;
  int h0 = blockIdx.x * 32;
  int b0 = blockIdx.y * 128;

  floatx4 acc[4][2][2];  // [gate][mtile][ntile]
#pragma unroll
  for (int g = 0; g < 4; ++g)
#pragma unroll
    for (int i = 0; i < 2; ++i)
#pragma unroll
      for (int j = 0; j < 2; ++j) acc[g][i][j] = (floatx4){0.f, 0.f, 0.f, 0.f};

#pragma unroll 1
  for (int k0 = 0; k0 < 1024; k0 += 32) {
    __syncthreads();
#pragma unroll
    for (int i = 0; i < 2; ++i) {
      int q = wave * 2 + i;
      // A: 128 rows of h
      GLDS(hprev + ((size_t)(b0 + q * 16 + srow) << 10) + k0 + scol,
           (char*)As + q * 1024 + lane * 16);
      // B: gate q>>1, half q&1 -> 16 rows of Wh_g
      GLDS(wT + ((size_t)(2 * (q >> 1) + 1) << 20) +
               ((size_t)(h0 + (q & 1) * 16 + srow) << 10) + k0 + scol,
           (char*)Bs + q * 1024 + lane * 16);
    }
    __syncthreads();
    short8 a[2], b[4][2];
#pragma unroll
    for (int i = 0; i < 2; ++i)
      a[i] = *(const short8*)(As + (wave * 32 + i * 16 + ln) * 32 + lq * 8);
#pragma unroll
    for (int g = 0; g < 4; ++g)
#pragma unroll
      for (int j = 0; j < 2; ++j)
        b[g][j] = *(const short8*)(Bs + (g * 32 + j * 16 + ln) * 32 + lq * 8);
#pragma unroll
    for (int g = 0; g < 4; ++g)
#pragma unroll
      for (int i = 0; i < 2; ++i)
#pragma unroll
        for (int j = 0; j < 2; ++j)
          acc[g][i][j] =
              __builtin_amdgcn_mfma_f32_16x16x32_bf16(a[i], b[g][j], acc[g][i][j], 0, 0, 0);
  }

  // register-local LSTM epilogue (C/D layout: col=lane&15, row=lq*4+r)
#pragma unroll
  for (int i = 0; i < 2; ++i) {
    int brow = b0 + wave * 32 + i * 16 + lq * 4;
#pragma unroll
    for (int j = 0; j < 2; ++j) {
      int hcol = h0 + j * 16 + ln;
      float bi = bias_c[hcol];
      float bf_ = bias_c[1024 + hcol];
      float bg = bias_c[2048 + hcol];
      float bo = bias_c[3072 + hcol];
#pragma unroll
      for (int r = 0; r < 4; ++r) {
        int row = brow + r;
        size_t idx = ((size_t)row << 10) + hcol;
        size_t xoff = (((size_t)tc << 10) + row) << 12;
        float pi = acc[0][i][j][r] + bf2f(xp[xoff + hcol]) + bi;
        float pf = acc[1][i][j][r] + bf2f(xp[xoff + 1024 + hcol]) + bf_;
        float pg = acc[2][i][j][r] + bf2f(xp[xoff + 2048 + hcol]) + bg;
        float po = acc[3][i][j][r] + bf2f(xp[xoff + 3072 + hcol]) + bo;
        float gi = 1.f / (1.f + __expf(-pi));
        float gf = 1.f / (1.f + __expf(-pf));
        float gg = 2.f / (1.f + __expf(-2.f * pg)) - 1.f;
        float go = 1.f / (1.f + __expf(-po));
        float cn = gf * c_ws[idx] + gi * gg;
        float hn = go * (2.f / (1.f + __expf(-2.f * cn)) - 1.f);
        c_ws[idx] = cn;
        hnext[idx] = (unsigned short)f2bf(hn);
        if (last) {
          out[idx] = hn;
          out[(1u << 20) + idx] = cn;
        }
      }
    }
  }
}

extern "C" void kernel_launch(void* const* d_in, const int* in_sizes, int n_in,
                              void* d_out, int out_size, void* d_ws, size_t ws_size,
                              hipStream_t stream) {
  const float* x = (const float*)d_in[0];
  char* ws = (char*)d_ws;
  unsigned short* wT = (unsigned short*)ws;                  // 16 MB
  float* bias_c = (float*)(ws + (16u << 20));                // 16 KB
  unsigned short* hb0 = (unsigned short*)(ws + (17u << 20)); // 2 MB
  unsigned short* hb1 = (unsigned short*)(ws + (19u << 20)); // 2 MB
  float* c_ws = (float*)(ws + (21u << 20));                  // 4 MB
  unsigned short* xb = (unsigned short*)(ws + (25u << 20));  // Tc*2 MB

  size_t base = 25u << 20;
  size_t per_t = 10u << 20;  // xb 2MB + xp 8MB per step
  int Tc = 1;
  if (ws_size > base + per_t) {
    size_t t = (ws_size - base) / per_t;
    Tc = t > 128 ? 128 : (int)t;
  }
  unsigned short* xp = xb + ((size_t)Tc << 20);  // after xb (Tc*1M shorts)

  for (int j = 0; j < 8; ++j)
    wtrans<<<dim3(32, 32), 256, 0, stream>>>((const float*)d_in[1 + j],
                                             wT + ((size_t)j << 20));
  bias_combine<<<16, 256, 0, stream>>>(
      (const float*)d_in[9], (const float*)d_in[10], (const float*)d_in[11],
      (const float*)d_in[12], (const float*)d_in[13], (const float*)d_in[14],
      (const float*)d_in[15], (const float*)d_in[16], bias_c);

  hipMemsetAsync(hb0, 0, 2u << 20, stream);
  hipMemsetAsync(c_ws, 0, 4u << 20, stream);

  float* out = (float*)d_out;
  int t = 0, parity = 0;
  for (int t0 = 0; t0 < Sdim; t0 += Tc) {
    int Tcur = (Sdim - t0) < Tc ? (Sdim - t0) : Tc;
    xconv<<<dim3(512, Tcur), 256, 0, stream>>>(x, xb, t0, Tcur);
    xgemm<<<dim3(32, Tcur * 8), 256, 0, stream>>>(xb, wT, xp, Tcur);
    for (int tc = 0; tc < Tcur; ++tc, ++t) {
      const unsigned short* hp = parity ? hb1 : hb0;
      unsigned short* hn = parity ? hb0 : hb1;
      lstm_step<<<dim3(32, 8), 256, 0, stream>>>(hp, hn, c_ws, wT, bias_c, xp, out,
                                                 tc, t == Sdim - 1);
      parity ^= 1;
    }
  }
}